// Round 28
// baseline (216.056 us; speedup 1.0000x reference)
//
#include <hip/hip_runtime.h>

#define NN 100000
#define NE 3200000
#define HD 20
#define EHD 64
#define EOUTD 10
#define TBINS 4096

// ---- radix/counting sort geometry ----
#define EPB 8192
#define NBLKS1 391                 // ceil(NE/EPB)
#define NBINS1 256                 // pass-1 bins: src>>9 in [0,196)
#define N1 (NBINS1 * NBLKS1)       // 100096
#define NBUCK 196
#define WIN 4096
#define WPB 6                      // windows per bucket
#define NWIN (NBUCK * WPB)         // 1176
#define N2 (NBUCK * 512 * WPB)     // 602112
#define KMASK 0x1FFFF              // low 17 bits = dst

// ---------------- scan1: per-1024-block exclusive + block sums ----------
__global__ void scan1_kernel(int* __restrict__ data, int* __restrict__ bsum, int n) {
    __shared__ int s[1024];
    int t = threadIdx.x;
    int i = blockIdx.x * 1024 + t;
    int v = (i < n) ? data[i] : 0;
    s[t] = v;
    __syncthreads();
    for (int off = 1; off < 1024; off <<= 1) {
        int add = (t >= off) ? s[t - off] : 0;
        __syncthreads();
        s[t] += add;
        __syncthreads();
    }
    if (i < n) data[i] = s[t] - v;            // exclusive, block-local
    if (t == 1023) bsum[blockIdx.x] = s[t];
}

// ---------------- scan3f: LDS-scan raw block sums, then add base ---------
__global__ void scan3f_kernel(int* __restrict__ data, const int* __restrict__ bsum,
                              int nb, int n) {
    __shared__ int s[1024];
    int t = threadIdx.x;
    int v = (t < nb) ? bsum[t] : 0;
    s[t] = v;
    __syncthreads();
    for (int off = 1; off < 1024; off <<= 1) {
        int add = (t >= off) ? s[t - off] : 0;
        __syncthreads();
        s[t] += add;
        __syncthreads();
    }
    __syncthreads();
    int i = blockIdx.x * 1024 + t;
    if (i < n) data[i] += s[i >> 10] - ((i >> 10) < nb ? bsum[i >> 10] : 0);
}

// ---------------- scan3bf: same for M2, also emits offsets ---------------
__global__ void scan3bf_kernel(int* __restrict__ data, const int* __restrict__ bsum,
                               int nb, int* __restrict__ offsets) {
    __shared__ int s[1024];
    int t = threadIdx.x;
    int v = (t < nb) ? bsum[t] : 0;
    s[t] = v;
    __syncthreads();
    for (int off = 1; off < 1024; off <<= 1) {
        int add = (t >= off) ? s[t - off] : 0;
        __syncthreads();
        s[t] += add;
        __syncthreads();
    }
    __syncthreads();
    int i = blockIdx.x * 1024 + t;
    if (i >= N2) return;
    int blk = i >> 10;
    int vv = data[i] + s[blk] - (blk < nb ? bsum[blk] : 0);
    data[i] = vv;
    if (i % WPB == 0) {
        int nbidx = i / WPB;                  // = bucket*512 + bin
        if (nbidx <= NN) offsets[nbidx] = vv;
    }
}

// ---------------- pass 1 histogram (bin = src>>9), 1024 threads ----------
__global__ void hist1_kernel(const int* __restrict__ ei, int* __restrict__ counts1) {
    __shared__ int h[NBINS1];
    int t = threadIdx.x;
    if (t < NBINS1) h[t] = 0;
    __syncthreads();
    int base = blockIdx.x * EPB;
    for (int j = t; j < EPB; j += 1024) {
        int e = base + j;
        if (e < NE) atomicAdd(&h[ei[e] >> 9], 1);
    }
    __syncthreads();
    if (t < NBINS1) counts1[t * NBLKS1 + blockIdx.x] = h[t];   // bin-major
}

// ---------------- pass 1 scatter: key packed into pk.x bits 17+ ----------
__global__ void scatter1_kernel(const int* __restrict__ ei,
                                const float* __restrict__ ea,
                                const int* __restrict__ counts1s,
                                int2* __restrict__ pk1) {
    __shared__ int cur[NBINS1];
    int t = threadIdx.x;
    if (t < NBINS1) cur[t] = counts1s[t * NBLKS1 + blockIdx.x];
    __syncthreads();
    int base = blockIdx.x * EPB;
    for (int j = t; j < EPB; j += 1024) {
        int e = base + j;
        if (e >= NE) break;
        int src = ei[e];
        int pos = atomicAdd(&cur[src >> 9], 1);
        int2 pk;
        pk.x = ei[NE + e] | ((src & 511) << 17);
        pk.y = __float_as_int(ea[e]);
        pk1[pos] = pk;
    }
}

// ---------------- pass 2 histogram (key from pk1.x bits 17+) -------------
__global__ void hist2_kernel(const int2* __restrict__ pk1,
                             const int* __restrict__ counts1s,
                             int* __restrict__ M2) {
    __shared__ int h[512];
    int t = threadIdx.x;
    h[t] = 0; h[t + 256] = 0;
    __syncthreads();
    int b = blockIdx.x / WPB, w = blockIdx.x % WPB;
    int bstart = counts1s[b * NBLKS1];
    int bend   = counts1s[(b + 1) * NBLKS1];
    int start = bstart + w * WIN;
    int end = (start + WIN < bend) ? (start + WIN) : bend;
    for (int i = start + t; i < end; i += 256)
        atomicAdd(&h[(pk1[i].x >> 17) & 511], 1);
    __syncthreads();
    M2[((b * 512) + t) * WPB + w]       = h[t];
    M2[((b * 512) + t + 256) * WPB + w] = h[t + 256];
}

// ---------------- pass 2 scatter: final pos + precompute (ti,fr,idx) ------
__global__ void scatter2_kernel(const int2* __restrict__ pk1,
                                const int* __restrict__ counts1s,
                                const int* __restrict__ M2s,
                                int2* __restrict__ csr_pk) {
    __shared__ int cur[512];
    int t = threadIdx.x;
    int b = blockIdx.x / WPB, w = blockIdx.x % WPB;
    cur[t]       = M2s[((b * 512) + t) * WPB + w];
    cur[t + 256] = M2s[((b * 512) + t + 256) * WPB + w];
    __syncthreads();
    int bstart = counts1s[b * NBLKS1];
    int bend   = counts1s[(b + 1) * NBLKS1];
    int start = bstart + w * WIN;
    int end = (start + WIN < bend) ? (start + WIN) : bend;
    for (int i = start + t; i < end; i += 256) {
        int2 pk = pk1[i];
        int pos = atomicAdd(&cur[(pk.x >> 17) & 511], 1);
        float d = __int_as_float(pk.y);
        int idx = (int)d; if (idx > 9) idx = 9;
        float u = d * ((float)TBINS / 10.0f);
        int ti = (int)u; if (ti > TBINS - 1) ti = TBINS - 1;
        float fr = u - (float)ti;
        int fr16 = (int)(fr * 65536.0f); if (fr16 > 65535) fr16 = 65535;
        pk.x &= KMASK;
        pk.y = fr16 | (ti << 16) | (idx << 28);
        csr_pk[pos] = pk;
    }
}

// ---------------- fused prep: tab2 pairs (blocks 0..15) + xbf4 (rest) -----
// tab2[ti*5+p] = { bf16(m0[p])|bf16(dm[p])<<16, bf16(m0[p+5])|bf16(dm[p+5])<<16 }
// xbf4[node*5+p] = { bf16(x[p])|bf16(x[p+5])<<16, bf16(x[p+10])|bf16(x[p+15])<<16 }
__global__ void prep_kernel(const float* __restrict__ W1,
                            const float* __restrict__ b1,
                            const float* __restrict__ W2,
                            const float* __restrict__ b2,
                            const float* __restrict__ x,
                            int2* __restrict__ tab2,
                            int2* __restrict__ xbf4) {
    const int TBLK = (TBINS + 255) / 256;      // 16 blocks for table
    auto bf16 = [](float f) -> unsigned int {
        unsigned int u = __float_as_uint(f);
        return (u + 0x7fffu + ((u >> 16) & 1u)) >> 16;
    };
    if (blockIdx.x < TBLK) {
        int i = blockIdx.x * 256 + threadIdx.x;
        if (i >= TBINS) return;
        float m0[EOUTD], m1[EOUTD];
        float d0 = (float)i * (10.0f / (float)TBINS);
        float d1 = (float)(i + 1) * (10.0f / (float)TBINS);
        #pragma unroll
        for (int j = 0; j < EOUTD; ++j) { m0[j] = b2[j]; m1[j] = b2[j]; }
        for (int k = 0; k < EHD; ++k) {
            float h0 = fmaxf(fmaf(d0, W1[k], b1[k]), 0.0f);
            float h1 = fmaxf(fmaf(d1, W1[k], b1[k]), 0.0f);
            #pragma unroll
            for (int j = 0; j < EOUTD; ++j) {
                m0[j] = fmaf(h0, W2[k * EOUTD + j], m0[j]);
                m1[j] = fmaf(h1, W2[k * EOUTD + j], m1[j]);
            }
        }
        #pragma unroll
        for (int p = 0; p < 5; ++p) {
            int2 tv;
            tv.x = (int)(bf16(m0[p]) | (bf16(m1[p] - m0[p]) << 16));
            tv.y = (int)(bf16(m0[p + 5]) | (bf16(m1[p + 5] - m0[p + 5]) << 16));
            tab2[(size_t)i * 5 + p] = tv;
        }
    } else {
        int t = (blockIdx.x - TBLK) * 256 + threadIdx.x;
        if (t >= NN * 5) return;
        int node = t / 5;
        int p = t - node * 5;
        const float* xp = x + (size_t)node * 2 * HD;
        int2 v;
        v.x = (int)(bf16(xp[p]) | (bf16(xp[p + 5]) << 16));
        v.y = (int)(bf16(xp[p + 10]) | (bf16(xp[p + 15]) << 16));
        xbf4[t] = v;
    }
}

// ---------------- node-owner kernel: 5 lanes/node, 4 features/lane --------
__launch_bounds__(256)
__global__ void node_kernel(const int* __restrict__ offsets,
                            const int2* __restrict__ csr_pk,
                            const float* __restrict__ x,
                            const int2* __restrict__ xbf4,
                            const int2* __restrict__ tab2,
                            const float* __restrict__ pa,
                            const float* __restrict__ pb,
                            const float* __restrict__ g1,
                            const float* __restrict__ g2,
                            const float* __restrict__ bias,
                            float* __restrict__ out) {
    int tid  = threadIdx.x;
    int wave = tid >> 6;
    int lane = tid & 63;
    int sub  = lane / 5;                   // 0..11 active, 12 = idle lanes
    int fk   = lane - sub * 5;             // feature group id 0..4
    int node = blockIdx.x * 48 + wave * 12 + sub;
    bool active = (sub < 12) && (node < NN);

    float a = pa[0], bb = pb[0];
    float oma = 1.0f - a;

    int off0 = 0, deg = 0;
    float xs0 = 0.0f, xs1 = 0.0f, xs2 = 0.0f, xs3 = 0.0f;
    if (active) {
        off0 = offsets[node];
        deg  = offsets[node + 1] - off0;
        const float* xp = x + (size_t)node * 2 * HD;
        xs0 = xp[fk]; xs1 = xp[fk + 5]; xs2 = xp[fk + 10]; xs3 = xp[fk + 15];
    }
    float ax0 = a * xs0, ax1 = a * xs1, ax2 = a * xs2, ax3 = a * xs3;

    float S00 = 0.0f, S10 = 0.0f, Sr0 = 0.0f;   // feature fk     (one-hot)
    float S01 = 0.0f, S11 = 0.0f, Sr1 = 0.0f;   // feature fk+5   (one-hot)
    float S02 = 0.0f, S12 = 0.0f, Sr2 = 0.0f;   // feature fk+10  (table)
    float S03 = 0.0f, S13 = 0.0f, Sr3 = 0.0f;   // feature fk+15  (table)

    auto process = [&](int dst, int dy) {
        int ti  = (dy >> 16) & 0xFFF;
        int idx = (dy >> 28) & 0xF;
        float fr = (float)(dy & 0xFFFF) * (1.0f / 65536.0f);
        int2 xw = xbf4[(size_t)(unsigned int)dst * 5 + fk];
        int2 tv = tab2[(size_t)ti * 5 + fk];
        float xd0 = __uint_as_float(((unsigned int)xw.x) << 16);
        float xd1 = __uint_as_float(((unsigned int)xw.x) & 0xffff0000u);
        float xd2 = __uint_as_float(((unsigned int)xw.y) << 16);
        float xd3 = __uint_as_float(((unsigned int)xw.y) & 0xffff0000u);
        float t0 = fmaf(-oma, xd0, ax0);
        float t1 = fmaf(-oma, xd1, ax1);
        float t2 = fmaf(-oma, xd2, ax2);
        float t3 = fmaf(-oma, xd3, ax3);
        float r0 = (t0 != 0.0f)
            ? __builtin_amdgcn_exp2f(bb * __builtin_amdgcn_logf(fabsf(t0))) : 0.0f;
        float r1 = (t1 != 0.0f)
            ? __builtin_amdgcn_exp2f(bb * __builtin_amdgcn_logf(fabsf(t1))) : 0.0f;
        float r2 = (t2 != 0.0f)
            ? __builtin_amdgcn_exp2f(bb * __builtin_amdgcn_logf(fabsf(t2))) : 0.0f;
        float r3 = (t3 != 0.0f)
            ? __builtin_amdgcn_exp2f(bb * __builtin_amdgcn_logf(fabsf(t3))) : 0.0f;
        Sr0 += r0; Sr1 += r1; Sr2 += r2; Sr3 += r3;
        float c0 = (idx == fk) ? 1.0f : 0.0f;
        float c1 = (idx == fk + 5) ? 1.0f : 0.0f;
        float va = __uint_as_float(((unsigned int)tv.x) << 16);
        float da = __uint_as_float(((unsigned int)tv.x) & 0xffff0000u);
        float vb = __uint_as_float(((unsigned int)tv.y) << 16);
        float db2 = __uint_as_float(((unsigned int)tv.y) & 0xffff0000u);
        float c2 = fmaxf(fmaf(fr, da, va), 0.0f);
        float c3 = fmaxf(fmaf(fr, db2, vb), 0.0f);
        S00 += c0; S10 = fmaf(r0, c0, S10);
        S01 += c1; S11 = fmaf(r1, c1, S11);
        S02 += c2; S12 = fmaf(r2, c2, S12);
        S03 += c3; S13 = fmaf(r3, c3, S13);
    };

    for (int base = 0; base < deg; base += 5) {
        int nchunk = deg - base; if (nchunk > 5) nchunk = 5;
        int idxc = off0 + base + ((fk < nchunk) ? fk : (nchunk - 1));
        int2 pk = csr_pk[idxc];
        int dstv = pk.x, dbits = pk.y;
        int jj = 0;
        for (; jj + 1 < nchunk; jj += 2) {
            int dA = __shfl(dstv, sub * 5 + jj, 64);
            int bA = __shfl(dbits, sub * 5 + jj, 64);
            int dB = __shfl(dstv, sub * 5 + jj + 1, 64);
            int bB = __shfl(dbits, sub * 5 + jj + 1, 64);
            process(dA, bA);
            process(dB, bB);
        }
        if (jj < nchunk) {
            int dA = __shfl(dstv, sub * 5 + jj, 64);
            int bA = __shfl(dbits, sub * 5 + jj, 64);
            process(dA, bA);
        }
    }

    float sf0 = (S00 != 0.0f) ? (S10 / S00) : (0.01f * Sr0);
    float sf1 = (S01 != 0.0f) ? (S11 / S01) : (0.01f * Sr1);
    float sf2 = (S02 != 0.0f) ? (S12 / S02) : (0.01f * Sr2);
    float sf3 = (S03 != 0.0f) ? (S13 / S03) : (0.01f * Sr3);

    if (active) {
        // epilogue: lane fk computes output rows fk, fk+5, fk+10, fk+15
        int r0 = fk, r1 = fk + 5, r2 = fk + 10, r3 = fk + 15;
        float a0 = bias[r0], a1 = bias[r1], a2 = bias[r2], a3 = bias[r3];
        const float* g10 = g1 + r0 * HD; const float* g20 = g2 + r0 * HD;
        const float* g11 = g1 + r1 * HD; const float* g21 = g2 + r1 * HD;
        const float* g12 = g1 + r2 * HD; const float* g22 = g2 + r2 * HD;
        const float* g13 = g1 + r3 * HD; const float* g23 = g2 + r3 * HD;
        #pragma unroll
        for (int j = 0; j < 5; ++j) {
            int sl = sub * 5 + j;
            float xa = __shfl(xs0, sl, 64), xb = __shfl(xs1, sl, 64);
            float xc = __shfl(xs2, sl, 64), xd = __shfl(xs3, sl, 64);
            float sa = __shfl(sf0, sl, 64), sb = __shfl(sf1, sl, 64);
            float sc = __shfl(sf2, sl, 64), sd = __shfl(sf3, sl, 64);
            a0 = fmaf(xa, g10[j], a0); a0 = fmaf(xb, g10[j + 5], a0);
            a0 = fmaf(xc, g10[j + 10], a0); a0 = fmaf(xd, g10[j + 15], a0);
            a0 = fmaf(sa, g20[j], a0); a0 = fmaf(sb, g20[j + 5], a0);
            a0 = fmaf(sc, g20[j + 10], a0); a0 = fmaf(sd, g20[j + 15], a0);
            a1 = fmaf(xa, g11[j], a1); a1 = fmaf(xb, g11[j + 5], a1);
            a1 = fmaf(xc, g11[j + 10], a1); a1 = fmaf(xd, g11[j + 15], a1);
            a1 = fmaf(sa, g21[j], a1); a1 = fmaf(sb, g21[j + 5], a1);
            a1 = fmaf(sc, g21[j + 10], a1); a1 = fmaf(sd, g21[j + 15], a1);
            a2 = fmaf(xa, g12[j], a2); a2 = fmaf(xb, g12[j + 5], a2);
            a2 = fmaf(xc, g12[j + 10], a2); a2 = fmaf(xd, g12[j + 15], a2);
            a2 = fmaf(sa, g22[j], a2); a2 = fmaf(sb, g22[j + 5], a2);
            a2 = fmaf(sc, g22[j + 10], a2); a2 = fmaf(sd, g22[j + 15], a2);
            a3 = fmaf(xa, g13[j], a3); a3 = fmaf(xb, g13[j + 5], a3);
            a3 = fmaf(xc, g13[j + 10], a3); a3 = fmaf(xd, g13[j + 15], a3);
            a3 = fmaf(sa, g23[j], a3); a3 = fmaf(sb, g23[j + 5], a3);
            a3 = fmaf(sc, g23[j + 10], a3); a3 = fmaf(sd, g23[j + 15], a3);
        }
        float* op = out + (size_t)node * 2 * HD;
        op[r0] = fmaxf(a0, 0.0f);
        op[r1] = fmaxf(a1, 0.0f);
        op[r2] = fmaxf(a2, 0.0f);
        op[r3] = fmaxf(a3, 0.0f);
        op[HD + r0] = sf0;
        op[HD + r1] = sf1;
        op[HD + r2] = sf2;
        op[HD + r3] = sf3;
    }
}

extern "C" void kernel_launch(void* const* d_in, const int* in_sizes, int n_in,
                              void* d_out, int out_size, void* d_ws, size_t ws_size,
                              hipStream_t stream) {
    const float* x    = (const float*)d_in[0];
    const int*   ei   = (const int*)d_in[1];
    const float* ea   = (const float*)d_in[2];
    const float* pa   = (const float*)d_in[3];
    const float* pb   = (const float*)d_in[4];
    const float* g1   = (const float*)d_in[5];
    const float* g2   = (const float*)d_in[6];
    const float* bias = (const float*)d_in[7];
    const float* W1   = (const float*)d_in[8];
    const float* b1   = (const float*)d_in[9];
    const float* W2   = (const float*)d_in[10];
    const float* b2   = (const float*)d_in[11];
    float* out = (float*)d_out;

    // workspace layout (all segments 128B-aligned)
    char* ws = (char*)d_ws;
    int*   counts1 = (int*)ws;     ws += ((size_t)N1 * 4 + 127) / 128 * 128;
    int*   bsum1   = (int*)ws;     ws += (1024 * 4 + 127) / 128 * 128;
    int*   M2      = (int*)ws;     ws += ((size_t)N2 * 4 + 127) / 128 * 128;
    int*   bsum2   = (int*)ws;     ws += (1024 * 4 + 127) / 128 * 128;
    int*   offsets = (int*)ws;     ws += ((size_t)(NN + 1) * 4 + 127) / 128 * 128;
    int2*  pk1     = (int2*)ws;    ws += (size_t)NE * 8;
    int2*  csr_pk  = (int2*)ws;    ws += (size_t)NE * 8;
    int2*  tab2    = (int2*)ws;    ws += ((size_t)TBINS * 5 * 8 + 127) / 128 * 128;
    int2*  xbf4    = (int2*)ws;    ws += ((size_t)NN * 5 * 8 + 127) / 128 * 128;

    const int TBLK = (TBINS + 255) / 256;
    prep_kernel<<<TBLK + (NN * 5 + 255) / 256, 256, 0, stream>>>(W1, b1, W2, b2, x,
                                                                 tab2, xbf4);

    // pass 1: group by bucket (src>>9)
    const int nb1 = (N1 + 1023) / 1024;
    hist1_kernel<<<NBLKS1, 1024, 0, stream>>>(ei, counts1);
    scan1_kernel<<<nb1, 1024, 0, stream>>>(counts1, bsum1, N1);
    scan3f_kernel<<<nb1, 1024, 0, stream>>>(counts1, bsum1, nb1, N1);
    scatter1_kernel<<<NBLKS1, 1024, 0, stream>>>(ei, ea, counts1, pk1);

    // pass 2: within bucket, bin = src & 511 (== exact node)
    const int nb2 = (N2 + 1023) / 1024;
    hist2_kernel<<<NWIN, 256, 0, stream>>>(pk1, counts1, M2);
    scan1_kernel<<<nb2, 1024, 0, stream>>>(M2, bsum2, N2);
    scan3bf_kernel<<<nb2, 1024, 0, stream>>>(M2, bsum2, nb2, offsets);
    scatter2_kernel<<<NWIN, 256, 0, stream>>>(pk1, counts1, M2, csr_pk);

    node_kernel<<<(NN + 47) / 48, 256, 0, stream>>>(offsets, csr_pk, x, xbf4, tab2,
                                                    pa, pb, g1, g2, bias, out);
}

// Round 29
// 174.388 us; speedup vs baseline: 1.2389x; 1.2389x over previous
//
#include <hip/hip_runtime.h>

#define NN 100000
#define NE 3200000
#define HD 20
#define EHD 64
#define EOUTD 10
#define TBINS 4096

// ---- radix/counting sort geometry ----
#define EPB 8192
#define NBLKS1 391                 // ceil(NE/EPB)
#define NBINS1 256                 // pass-1 bins: src>>9 in [0,196)
#define N1 (NBINS1 * NBLKS1)       // 100096
#define NBUCK 196
#define WIN 4096
#define WPB 6                      // windows per bucket
#define NWIN (NBUCK * WPB)         // 1176
#define N2 (NBUCK * 512 * WPB)     // 602112
#define KMASK 0x1FFFF              // low 17 bits = dst

// ---------------- scan1: per-1024-block exclusive + block sums ----------
__global__ void scan1_kernel(int* __restrict__ data, int* __restrict__ bsum, int n) {
    __shared__ int s[1024];
    int t = threadIdx.x;
    int i = blockIdx.x * 1024 + t;
    int v = (i < n) ? data[i] : 0;
    s[t] = v;
    __syncthreads();
    for (int off = 1; off < 1024; off <<= 1) {
        int add = (t >= off) ? s[t - off] : 0;
        __syncthreads();
        s[t] += add;
        __syncthreads();
    }
    if (i < n) data[i] = s[t] - v;            // exclusive, block-local
    if (t == 1023) bsum[blockIdx.x] = s[t];
}

// ---------------- scan3f: LDS-scan raw block sums, then add base ---------
__global__ void scan3f_kernel(int* __restrict__ data, const int* __restrict__ bsum,
                              int nb, int n) {
    __shared__ int s[1024];
    int t = threadIdx.x;
    int v = (t < nb) ? bsum[t] : 0;
    s[t] = v;
    __syncthreads();
    for (int off = 1; off < 1024; off <<= 1) {
        int add = (t >= off) ? s[t - off] : 0;
        __syncthreads();
        s[t] += add;
        __syncthreads();
    }
    __syncthreads();
    int i = blockIdx.x * 1024 + t;
    if (i < n) data[i] += s[i >> 10] - ((i >> 10) < nb ? bsum[i >> 10] : 0);
}

// ---------------- scan3bf: same for M2, also emits offsets ---------------
__global__ void scan3bf_kernel(int* __restrict__ data, const int* __restrict__ bsum,
                               int nb, int* __restrict__ offsets) {
    __shared__ int s[1024];
    int t = threadIdx.x;
    int v = (t < nb) ? bsum[t] : 0;
    s[t] = v;
    __syncthreads();
    for (int off = 1; off < 1024; off <<= 1) {
        int add = (t >= off) ? s[t - off] : 0;
        __syncthreads();
        s[t] += add;
        __syncthreads();
    }
    __syncthreads();
    int i = blockIdx.x * 1024 + t;
    if (i >= N2) return;
    int blk = i >> 10;
    int vv = data[i] + s[blk] - (blk < nb ? bsum[blk] : 0);
    data[i] = vv;
    if (i % WPB == 0) {
        int nbidx = i / WPB;                  // = bucket*512 + bin
        if (nbidx <= NN) offsets[nbidx] = vv;
    }
}

// ---------------- pass 1 histogram (bin = src>>9), 1024 threads ----------
__global__ void hist1_kernel(const int* __restrict__ ei, int* __restrict__ counts1) {
    __shared__ int h[NBINS1];
    int t = threadIdx.x;
    if (t < NBINS1) h[t] = 0;
    __syncthreads();
    int base = blockIdx.x * EPB;
    for (int j = t; j < EPB; j += 1024) {
        int e = base + j;
        if (e < NE) atomicAdd(&h[ei[e] >> 9], 1);
    }
    __syncthreads();
    if (t < NBINS1) counts1[t * NBLKS1 + blockIdx.x] = h[t];   // bin-major
}

// ---------------- pass 1 scatter: key packed into pk.x bits 17+ ----------
__global__ void scatter1_kernel(const int* __restrict__ ei,
                                const float* __restrict__ ea,
                                const int* __restrict__ counts1s,
                                int2* __restrict__ pk1) {
    __shared__ int cur[NBINS1];
    int t = threadIdx.x;
    if (t < NBINS1) cur[t] = counts1s[t * NBLKS1 + blockIdx.x];
    __syncthreads();
    int base = blockIdx.x * EPB;
    for (int j = t; j < EPB; j += 1024) {
        int e = base + j;
        if (e >= NE) break;
        int src = ei[e];
        int pos = atomicAdd(&cur[src >> 9], 1);
        int2 pk;
        pk.x = ei[NE + e] | ((src & 511) << 17);
        pk.y = __float_as_int(ea[e]);
        pk1[pos] = pk;
    }
}

// ---------------- pass 2 histogram (key from pk1.x bits 17+) -------------
__global__ void hist2_kernel(const int2* __restrict__ pk1,
                             const int* __restrict__ counts1s,
                             int* __restrict__ M2) {
    __shared__ int h[512];
    int t = threadIdx.x;
    h[t] = 0; h[t + 256] = 0;
    __syncthreads();
    int b = blockIdx.x / WPB, w = blockIdx.x % WPB;
    int bstart = counts1s[b * NBLKS1];
    int bend   = counts1s[(b + 1) * NBLKS1];
    int start = bstart + w * WIN;
    int end = (start + WIN < bend) ? (start + WIN) : bend;
    for (int i = start + t; i < end; i += 256)
        atomicAdd(&h[(pk1[i].x >> 17) & 511], 1);
    __syncthreads();
    M2[((b * 512) + t) * WPB + w]       = h[t];
    M2[((b * 512) + t + 256) * WPB + w] = h[t + 256];
}

// ---------------- pass 2 scatter: final pos + precompute (ti,fr,idx) ------
__global__ void scatter2_kernel(const int2* __restrict__ pk1,
                                const int* __restrict__ counts1s,
                                const int* __restrict__ M2s,
                                int2* __restrict__ csr_pk) {
    __shared__ int cur[512];
    int t = threadIdx.x;
    int b = blockIdx.x / WPB, w = blockIdx.x % WPB;
    cur[t]       = M2s[((b * 512) + t) * WPB + w];
    cur[t + 256] = M2s[((b * 512) + t + 256) * WPB + w];
    __syncthreads();
    int bstart = counts1s[b * NBLKS1];
    int bend   = counts1s[(b + 1) * NBLKS1];
    int start = bstart + w * WIN;
    int end = (start + WIN < bend) ? (start + WIN) : bend;
    for (int i = start + t; i < end; i += 256) {
        int2 pk = pk1[i];
        int pos = atomicAdd(&cur[(pk.x >> 17) & 511], 1);
        float d = __int_as_float(pk.y);
        int idx = (int)d; if (idx > 9) idx = 9;
        float u = d * ((float)TBINS / 10.0f);
        int ti = (int)u; if (ti > TBINS - 1) ti = TBINS - 1;
        float fr = u - (float)ti;
        int fr16 = (int)(fr * 65536.0f); if (fr16 > 65535) fr16 = 65535;
        pk.x &= KMASK;
        pk.y = fr16 | (ti << 16) | (idx << 28);
        csr_pk[pos] = pk;
    }
}

// ---------------- fused prep: tab rows (blocks 0..15) + xbf2 (rest) ------
// tab[ti*32 + 2j] = bf16 val_j, tab[ti*32 + 2j+1] = bf16 delta_j
// xbf2[node*16 + k] = bf16(x[k]) | bf16(x[k+10])<<16, k=0..9
__global__ void prep_kernel(const float* __restrict__ W1,
                            const float* __restrict__ b1,
                            const float* __restrict__ W2,
                            const float* __restrict__ b2,
                            const float* __restrict__ x,
                            unsigned short* __restrict__ tab,
                            int* __restrict__ xbf2) {
    const int TBLK = (TBINS + 255) / 256;      // 16 blocks for table
    auto bf16 = [](float f) -> unsigned int {
        unsigned int u = __float_as_uint(f);
        return (u + 0x7fffu + ((u >> 16) & 1u)) >> 16;
    };
    if (blockIdx.x < TBLK) {
        int i = blockIdx.x * 256 + threadIdx.x;
        if (i >= TBINS) return;
        float m0[EOUTD], m1[EOUTD];
        float d0 = (float)i * (10.0f / (float)TBINS);
        float d1 = (float)(i + 1) * (10.0f / (float)TBINS);
        #pragma unroll
        for (int j = 0; j < EOUTD; ++j) { m0[j] = b2[j]; m1[j] = b2[j]; }
        for (int k = 0; k < EHD; ++k) {
            float h0 = fmaxf(fmaf(d0, W1[k], b1[k]), 0.0f);
            float h1 = fmaxf(fmaf(d1, W1[k], b1[k]), 0.0f);
            #pragma unroll
            for (int j = 0; j < EOUTD; ++j) {
                m0[j] = fmaf(h0, W2[k * EOUTD + j], m0[j]);
                m1[j] = fmaf(h1, W2[k * EOUTD + j], m1[j]);
            }
        }
        unsigned short* row = tab + (size_t)i * 32;
        #pragma unroll
        for (int j = 0; j < EOUTD; ++j) {
            row[2 * j]     = (unsigned short)bf16(m0[j]);
            row[2 * j + 1] = (unsigned short)bf16(m1[j] - m0[j]);
        }
        #pragma unroll
        for (int j = 20; j < 32; ++j) row[j] = 0;
    } else {
        int t = (blockIdx.x - TBLK) * 256 + threadIdx.x;
        if (t >= NN * 16) return;
        int node = t >> 4, k = t & 15;
        int v = 0;
        if (k < 10) {
            v = (int)(bf16(x[(size_t)node * 2 * HD + k])
                      | (bf16(x[(size_t)node * 2 * HD + k + 10]) << 16));
        }
        xbf2[t] = v;
    }
}

// ---------------- node-owner kernel: 10 lanes/node, 2 features/lane -------
__launch_bounds__(256)
__global__ void node_kernel(const int* __restrict__ offsets,
                            const int2* __restrict__ csr_pk,
                            const float* __restrict__ x,
                            const int* __restrict__ xbf2,
                            const unsigned short* __restrict__ tab,
                            const float* __restrict__ pa,
                            const float* __restrict__ pb,
                            const float* __restrict__ g1,
                            const float* __restrict__ g2,
                            const float* __restrict__ bias,
                            float* __restrict__ out) {
    int tid  = threadIdx.x;
    int wave = tid >> 6;
    int lane = tid & 63;
    int sub  = lane / 10;                  // 0..5 active, 6 = idle lanes
    int fk   = lane - sub * 10;            // feature pair id 0..9
    int node = blockIdx.x * 24 + wave * 6 + sub;
    bool active = (sub < 6) && (node < NN);

    float a = pa[0], bb = pb[0];
    float oma = 1.0f - a;

    int off0 = 0, deg = 0;
    float xs_lo = 0.0f, xs_hi = 0.0f, axs_lo = 0.0f, axs_hi = 0.0f;
    if (active) {
        off0 = offsets[node];
        deg  = offsets[node + 1] - off0;
        xs_lo = x[(size_t)node * 2 * HD + fk];
        xs_hi = x[(size_t)node * 2 * HD + fk + 10];
        axs_lo = a * xs_lo;
        axs_hi = a * xs_hi;
    }

    float S0a = 0.0f, S1a = 0.0f, Sra = 0.0f;   // feature fk (one-hot)
    float S0b = 0.0f, S1b = 0.0f, Srb = 0.0f;   // feature fk+10 (table)

    auto process = [&](int dst, int dy) {
        int ti  = (dy >> 16) & 0xFFF;
        int idx = (dy >> 28) & 0xF;
        float fr = (float)(dy & 0xFFFF) * (1.0f / 65536.0f);
        unsigned int xw = (unsigned int)xbf2[(((size_t)(unsigned int)dst) << 4) + fk];
        unsigned int tv = *(const unsigned int*)(tab + (((size_t)ti) << 5) + fk * 2);
        float xd_lo = __uint_as_float(xw << 16);
        float xd_hi = __uint_as_float(xw & 0xffff0000u);
        float t0 = fmaf(-oma, xd_lo, axs_lo);
        float t1 = fmaf(-oma, xd_hi, axs_hi);
        float r0 = (t0 != 0.0f)
            ? __builtin_amdgcn_exp2f(bb * __builtin_amdgcn_logf(fabsf(t0))) : 0.0f;
        float r1 = (t1 != 0.0f)
            ? __builtin_amdgcn_exp2f(bb * __builtin_amdgcn_logf(fabsf(t1))) : 0.0f;
        Sra += r0; Srb += r1;
        float c0 = (fk == idx) ? 1.0f : 0.0f;
        float val = __uint_as_float(tv << 16);
        float del = __uint_as_float(tv & 0xffff0000u);
        float c1 = fmaxf(fmaf(fr, del, val), 0.0f);
        S0a += c0; S1a = fmaf(r0, c0, S1a);
        S0b += c1; S1b = fmaf(r1, c1, S1b);
    };

    for (int base = 0; base < deg; base += 10) {
        int nchunk = deg - base; if (nchunk > 10) nchunk = 10;
        // clamped (branch-free) coalesced preload of this chunk's (dst,d)
        int idxc = off0 + base + ((fk < nchunk) ? fk : (nchunk - 1));
        int2 pk = csr_pk[idxc];
        int dstv = pk.x, dbits = pk.y;
        int jj = 0;
        for (; jj + 1 < nchunk; jj += 2) {
            int dA = __shfl(dstv, sub * 10 + jj, 64);
            int bA = __shfl(dbits, sub * 10 + jj, 64);
            int dB = __shfl(dstv, sub * 10 + jj + 1, 64);
            int bB = __shfl(dbits, sub * 10 + jj + 1, 64);
            process(dA, bA);
            process(dB, bB);
        }
        if (jj < nchunk) {
            int dA = __shfl(dstv, sub * 10 + jj, 64);
            int bA = __shfl(dbits, sub * 10 + jj, 64);
            process(dA, bA);
        }
    }

    float sf_lo = (S0a != 0.0f) ? (S1a / S0a) : (0.01f * Sra);
    float sf_hi = (S0b != 0.0f) ? (S1b / S0b) : (0.01f * Srb);

    if (active) {
        // epilogue: lane fk computes output rows fk and fk+10
        float acc0 = bias[fk];
        float acc1 = bias[fk + 10];
        const float* g1r0 = g1 + fk * HD;
        const float* g1r1 = g1 + (fk + 10) * HD;
        const float* g2r0 = g2 + fk * HD;
        const float* g2r1 = g2 + (fk + 10) * HD;
        #pragma unroll
        for (int j = 0; j < 10; ++j) {
            int sl = sub * 10 + j;
            float xj  = __shfl(xs_lo, sl, 64);
            float xj1 = __shfl(xs_hi, sl, 64);
            float sj  = __shfl(sf_lo, sl, 64);
            float sj1 = __shfl(sf_hi, sl, 64);
            acc0 = fmaf(xj, g1r0[j], acc0);  acc0 = fmaf(xj1, g1r0[j + 10], acc0);
            acc0 = fmaf(sj, g2r0[j], acc0);  acc0 = fmaf(sj1, g2r0[j + 10], acc0);
            acc1 = fmaf(xj, g1r1[j], acc1);  acc1 = fmaf(xj1, g1r1[j + 10], acc1);
            acc1 = fmaf(sj, g2r1[j], acc1);  acc1 = fmaf(sj1, g2r1[j + 10], acc1);
        }
        float* op = out + (size_t)node * 2 * HD;
        op[fk]          = fmaxf(acc0, 0.0f);
        op[fk + 10]     = fmaxf(acc1, 0.0f);
        op[HD + fk]     = sf_lo;
        op[HD + fk + 10] = sf_hi;
    }
}

extern "C" void kernel_launch(void* const* d_in, const int* in_sizes, int n_in,
                              void* d_out, int out_size, void* d_ws, size_t ws_size,
                              hipStream_t stream) {
    const float* x    = (const float*)d_in[0];
    const int*   ei   = (const int*)d_in[1];
    const float* ea   = (const float*)d_in[2];
    const float* pa   = (const float*)d_in[3];
    const float* pb   = (const float*)d_in[4];
    const float* g1   = (const float*)d_in[5];
    const float* g2   = (const float*)d_in[6];
    const float* bias = (const float*)d_in[7];
    const float* W1   = (const float*)d_in[8];
    const float* b1   = (const float*)d_in[9];
    const float* W2   = (const float*)d_in[10];
    const float* b2   = (const float*)d_in[11];
    float* out = (float*)d_out;

    // workspace layout (all segments 128B-aligned)
    char* ws = (char*)d_ws;
    int*   counts1 = (int*)ws;     ws += ((size_t)N1 * 4 + 127) / 128 * 128;
    int*   bsum1   = (int*)ws;     ws += (1024 * 4 + 127) / 128 * 128;
    int*   M2      = (int*)ws;     ws += ((size_t)N2 * 4 + 127) / 128 * 128;
    int*   bsum2   = (int*)ws;     ws += (1024 * 4 + 127) / 128 * 128;
    int*   offsets = (int*)ws;     ws += ((size_t)(NN + 1) * 4 + 127) / 128 * 128;
    int2*  pk1     = (int2*)ws;    ws += (size_t)NE * 8;
    int2*  csr_pk  = (int2*)ws;    ws += (size_t)NE * 8;
    unsigned short* tab = (unsigned short*)ws;   ws += ((size_t)TBINS * 32 * 2 + 127) / 128 * 128;
    int*   xbf2    = (int*)ws;     ws += ((size_t)NN * 16 * 4 + 127) / 128 * 128;

    const int TBLK = (TBINS + 255) / 256;
    prep_kernel<<<TBLK + (NN * 16 + 255) / 256, 256, 0, stream>>>(W1, b1, W2, b2, x,
                                                                  tab, xbf2);

    // pass 1: group by bucket (src>>9)
    const int nb1 = (N1 + 1023) / 1024;
    hist1_kernel<<<NBLKS1, 1024, 0, stream>>>(ei, counts1);
    scan1_kernel<<<nb1, 1024, 0, stream>>>(counts1, bsum1, N1);
    scan3f_kernel<<<nb1, 1024, 0, stream>>>(counts1, bsum1, nb1, N1);
    scatter1_kernel<<<NBLKS1, 1024, 0, stream>>>(ei, ea, counts1, pk1);

    // pass 2: within bucket, bin = src & 511 (== exact node)
    const int nb2 = (N2 + 1023) / 1024;
    hist2_kernel<<<NWIN, 256, 0, stream>>>(pk1, counts1, M2);
    scan1_kernel<<<nb2, 1024, 0, stream>>>(M2, bsum2, N2);
    scan3bf_kernel<<<nb2, 1024, 0, stream>>>(M2, bsum2, nb2, offsets);
    scatter2_kernel<<<NWIN, 256, 0, stream>>>(pk1, counts1, M2, csr_pk);

    node_kernel<<<(NN + 23) / 24, 256, 0, stream>>>(offsets, csr_pk, x, xbf2, tab,
                                                    pa, pb, g1, g2, bias, out);
}